// Round 1
// baseline (463.251 us; speedup 1.0000x reference)
//
#include <hip/hip_runtime.h>

#define CRACK_VAL 0.05f

// Kernel A: out = clamp(x, 0, 1), vectorized float4.
__global__ void __launch_bounds__(256) lenscrack_clamp_copy(
    const float4* __restrict__ in, float4* __restrict__ out, int n4) {
    int i = blockIdx.x * blockDim.x + threadIdx.x;
    if (i < n4) {
        float4 v = in[i];
        v.x = fminf(fmaxf(v.x, 0.0f), 1.0f);
        v.y = fminf(fmaxf(v.y, 0.0f), 1.0f);
        v.z = fminf(fmaxf(v.z, 0.0f), 1.0f);
        v.w = fminf(fmaxf(v.w, 0.0f), 1.0f);
        out[i] = v;
    }
}

// Kernel B: one thread per crack line; exact mirror of the reference's
// Bresenham variant (record BEFORE update; strict e2 > -dy / e2 < dx,
// both conditions evaluated on the same e2; t runs 0..nsteps inclusive).
// Writes CRACK_VAL to all 3 channels of each covered pixel.
__global__ void lenscrack_raster(
    const int* __restrict__ ep, float* __restrict__ out,
    int B, int K, int C, int H, int W) {
    int tid = blockIdx.x * blockDim.x + threadIdx.x;
    if (tid >= B * K) return;
    int b = tid / K;
    const int* e = ep + (size_t)tid * 4;
    int y0 = e[0], x0 = e[1], y1 = e[2], x1 = e[3];
    int dx = abs(x1 - x0);
    int dy = abs(y1 - y0);
    int sx = (x0 < x1) ? 1 : -1;
    int sy = (y0 < y1) ? 1 : -1;
    int nsteps = max(dx, dy);

    size_t HW = (size_t)H * W;
    float* base = out + (size_t)b * C * HW;

    int x = x0, y = y0, err = dx - dy;
    for (int t = 0; t <= nsteps; ++t) {
        if (x >= 0 && x < W && y >= 0 && y < H) {
            size_t off = (size_t)y * W + (size_t)x;
            base[off]          = CRACK_VAL;
            base[off + HW]     = CRACK_VAL;
            base[off + 2 * HW] = CRACK_VAL;
        }
        int e2 = 2 * err;
        // Both conditions use the SAME e2 (pre-update), like the reference.
        bool cx = (e2 > -dy);
        bool cy = (e2 < dx);
        if (cx) { err -= dy; x += sx; }
        if (cy) { err += dx; y += sy; }
    }
}

extern "C" void kernel_launch(void* const* d_in, const int* in_sizes, int n_in,
                              void* d_out, int out_size, void* d_ws, size_t ws_size,
                              hipStream_t stream) {
    const float* x  = (const float*)d_in[0];
    const int*   ep = (const int*)d_in[1];
    float* out = (float*)d_out;

    const int B = 16, C = 3, H = 1024, W = 1024, K = 8;

    // Kernel A: full clamp-copy (out_size = B*C*H*W, divisible by 4).
    int n4 = out_size / 4;
    int block = 256;
    int grid = (n4 + block - 1) / block;
    lenscrack_clamp_copy<<<grid, block, 0, stream>>>(
        (const float4*)x, (float4*)out, n4);

    // Kernel B: scatter CRACK_VAL along the 128 crack lines.
    int nlines = B * K;
    lenscrack_raster<<<(nlines + 127) / 128, 128, 0, stream>>>(
        ep, out, B, K, C, H, W);
}

// Round 2
// 395.102 us; speedup vs baseline: 1.1725x; 1.1725x over previous
//
#include <hip/hip_runtime.h>

#define CRACK_VAL 0.05f

// Kernel A: out = clamp(x, 0, 1), vectorized float4.
__global__ void __launch_bounds__(256) lenscrack_clamp_copy(
    const float4* __restrict__ in, float4* __restrict__ out, int n4) {
    int i = blockIdx.x * blockDim.x + threadIdx.x;
    if (i < n4) {
        float4 v = in[i];
        v.x = fminf(fmaxf(v.x, 0.0f), 1.0f);
        v.y = fminf(fmaxf(v.y, 0.0f), 1.0f);
        v.z = fminf(fmaxf(v.z, 0.0f), 1.0f);
        v.w = fminf(fmaxf(v.w, 0.0f), 1.0f);
        out[i] = v;
    }
}

// Kernel B: ONE BLOCK PER LINE. Thread 0 serially walks the reference's exact
// Bresenham variant (record BEFORE update; strict e2 > -dy / e2 < dx, both
// conditions on the same pre-update e2; t = 0..nsteps inclusive), writing
// in-bounds pixel offsets (y*W+x) into LDS. Then 256 threads scatter
// CRACK_VAL to all 3 channels in parallel.
#define MAXT 1024  // T = max(H, W)

__global__ void __launch_bounds__(256) lenscrack_raster(
    const int* __restrict__ ep, float* __restrict__ out,
    int K, int C, int H, int W) {
    __shared__ int offs[MAXT];

    // Parallel init to "invalid".
    for (int t = threadIdx.x; t < MAXT; t += 256) offs[t] = -1;
    __syncthreads();

    int line = blockIdx.x;           // 0 .. B*K-1
    int b = line / K;

    if (threadIdx.x == 0) {
        const int* e = ep + (size_t)line * 4;
        int y0 = e[0], x0 = e[1], y1 = e[2], x1 = e[3];
        int dx = abs(x1 - x0);
        int dy = abs(y1 - y0);
        int sx = (x0 < x1) ? 1 : -1;
        int sy = (y0 < y1) ? 1 : -1;
        int nsteps = max(dx, dy);    // <= MAXT-1 since coords in [0, 1024)

        int x = x0, y = y0, err = dx - dy;
        for (int t = 0; t <= nsteps; ++t) {
            if (x >= 0 && x < W && y >= 0 && y < H)
                offs[t] = y * W + x;
            int e2 = 2 * err;
            bool cx = (e2 > -dy);    // same pre-update e2 for both conds
            bool cy = (e2 < dx);
            if (cx) { err -= dy; x += sx; }
            if (cy) { err += dx; y += sy; }
        }
    }
    __syncthreads();

    size_t HW = (size_t)H * W;
    float* base = out + (size_t)b * C * HW;
    // 3 channels x MAXT entries; consecutive threads take consecutive t
    // (contiguous addresses along x-major lines -> coalesced stores).
    for (int i = threadIdx.x; i < C * MAXT; i += 256) {
        int t = i & (MAXT - 1);
        int c = i >> 10;             // MAXT = 1024
        int o = offs[t];
        if (o >= 0) base[(size_t)c * HW + o] = CRACK_VAL;
    }
}

extern "C" void kernel_launch(void* const* d_in, const int* in_sizes, int n_in,
                              void* d_out, int out_size, void* d_ws, size_t ws_size,
                              hipStream_t stream) {
    const float* x  = (const float*)d_in[0];
    const int*   ep = (const int*)d_in[1];
    float* out = (float*)d_out;

    const int B = 16, C = 3, H = 1024, W = 1024, K = 8;

    // Kernel A: full clamp-copy (out_size = B*C*H*W, divisible by 4).
    int n4 = out_size / 4;
    int block = 256;
    int grid = (n4 + block - 1) / block;
    lenscrack_clamp_copy<<<grid, block, 0, stream>>>(
        (const float4*)x, (float4*)out, n4);

    // Kernel B: one block per crack line.
    lenscrack_raster<<<B * K, 256, 0, stream>>>(ep, out, K, C, H, W);
}

// Round 3
// 328.240 us; speedup vs baseline: 1.4113x; 1.2037x over previous
//
#include <hip/hip_runtime.h>

#define CRACK_VAL 0.05f

// Kernel A: out = clamp(x, 0, 1), vectorized float4.
__global__ void __launch_bounds__(256) lenscrack_clamp_copy(
    const float4* __restrict__ in, float4* __restrict__ out, int n4) {
    int i = blockIdx.x * blockDim.x + threadIdx.x;
    if (i < n4) {
        float4 v = in[i];
        v.x = fminf(fmaxf(v.x, 0.0f), 1.0f);
        v.y = fminf(fmaxf(v.y, 0.0f), 1.0f);
        v.z = fminf(fmaxf(v.z, 0.0f), 1.0f);
        v.w = fminf(fmaxf(v.w, 0.0f), 1.0f);
        out[i] = v;
    }
}

// Kernel B: fully parallel closed-form Bresenham raster.
// Reference is standard Wikipedia Bresenham (record position BEFORE the
// update; e2 = 2*err; e2 > -dy -> x-step; e2 < dx -> y-step). For this
// variant the major axis advances every iteration and the minor coordinate
// at step t (the value RECORDED at t) is:
//     minor(t) = floor((2*t*dmin + dmaj - 1) / (2*dmaj))
// Verified against step simulation for (dx,dy) in {(4,3),(3,4),(5,2),(2,1),
// (1,1023),(1023,1),(3,3)}. dmaj==0 (degenerate point) handled explicitly.
// One thread per (line, t): grid = B*K*4 blocks of 256 (t = 0..1023).
__global__ void __launch_bounds__(256) lenscrack_raster(
    const int* __restrict__ ep, float* __restrict__ out,
    int K, int C, int H, int W) {
    int line = blockIdx.x >> 2;                     // 0 .. B*K-1
    int t    = ((blockIdx.x & 3) << 8) | threadIdx.x;  // 0 .. 1023

    const int* e = ep + (size_t)line * 4;           // broadcast load per wave
    int y0 = e[0], x0 = e[1], y1 = e[2], x1 = e[3];
    int dx = abs(x1 - x0);
    int dy = abs(y1 - y0);
    int sx = (x0 < x1) ? 1 : -1;
    int sy = (y0 < y1) ? 1 : -1;
    int dmaj = max(dx, dy);                         // nsteps
    if (t > dmaj) return;                           // t inclusive of nsteps

    int dmin = min(dx, dy);
    int minor = (dmaj > 0) ? (2 * t * dmin + dmaj - 1) / (2 * dmaj) : 0;

    bool xmaj = (dx >= dy);
    int x = x0 + sx * (xmaj ? t : minor);
    int y = y0 + sy * (xmaj ? minor : t);

    if (x >= 0 && x < W && y >= 0 && y < H) {
        int b = line / K;
        size_t HW = (size_t)H * W;
        float* base = out + (size_t)b * C * HW + (size_t)y * W + (size_t)x;
        base[0]      = CRACK_VAL;
        base[HW]     = CRACK_VAL;
        base[2 * HW] = CRACK_VAL;
    }
}

extern "C" void kernel_launch(void* const* d_in, const int* in_sizes, int n_in,
                              void* d_out, int out_size, void* d_ws, size_t ws_size,
                              hipStream_t stream) {
    const float* x  = (const float*)d_in[0];
    const int*   ep = (const int*)d_in[1];
    float* out = (float*)d_out;

    const int B = 16, C = 3, H = 1024, W = 1024, K = 8;

    // Kernel A: full clamp-copy (out_size = B*C*H*W, divisible by 4).
    int n4 = out_size / 4;
    int block = 256;
    int grid = (n4 + block - 1) / block;
    lenscrack_clamp_copy<<<grid, block, 0, stream>>>(
        (const float4*)x, (float4*)out, n4);

    // Kernel B: 4 blocks per line (1024 t-values / 256 threads).
    lenscrack_raster<<<B * K * 4, 256, 0, stream>>>(ep, out, K, C, H, W);
}